// Round 8
// baseline (1130.235 us; speedup 1.0000x reference)
//
#include <hip/hip_runtime.h>
#include <cmath>

typedef __bf16 bf16;
typedef __attribute__((ext_vector_type(8))) __bf16 bf16x8;
typedef __attribute__((ext_vector_type(4))) __bf16 bf16x4;
typedef __attribute__((ext_vector_type(4))) float f32x4;

#define NB 2
#define NSEQ 2048
#define NDIM 512
#define NHEADS 8
#define DHEAD 64
#define NMEM 16
#define NJ 2064
#define NJP 2176        // 17*128
#define NFF 2048
#define NROWS (NB*NSEQ) // 4096
#define STRIPE 1024     // i-rows per S stripe

enum { EPI_F32 = 0, EPI_SPLIT = 1, EPI_GELUSPLIT = 2, EPI_RESID = 3 };

// ---------------------------------------------------------------------------
// Split-precision GEMM (unchanged, used for projections/FF): fp32 operands as
// bf16 (hi,lo). C = Ah*Bh + Al*Bh + Ah*Bl, fp32 accum.
// ---------------------------------------------------------------------------
template<int BM, int BN, int WAVES_M, int WAVES_N, int EPI>
__global__ __launch_bounds__(256)
void gemm_split(const bf16* __restrict__ A, const bf16* __restrict__ B,
                void* __restrict__ Cv, const float* __restrict__ bias,
                int K, int lda, int ldb, int ldc, int loA, int loB,
                long long sAz, long long sBz, long long sCz, float scale)
{
  constexpr int BK = 32;
  constexpr int WM = BM / WAVES_M;
  constexpr int WN = BN / WAVES_N;
  constexpr int MF = WM / 16;
  constexpr int NF = WN / 16;
  constexpr int AI = (BM * BK * 2) / 4096;
  constexpr int BI = (BN * BK * 2) / 4096;
  __shared__ bf16 Ash[BM * BK];
  __shared__ bf16 Asl[BM * BK];
  __shared__ bf16 Bsh[BN * BK];
  __shared__ bf16 Bsl[BN * BK];

  const int z = blockIdx.z;
  A += (long long)z * sAz;
  B += (long long)z * sBz;
  const int bm0 = blockIdx.x * BM;
  const int bn0 = blockIdx.y * BN;
  const int t = threadIdx.x;
  const int wave = t >> 6, lane = t & 63;
  const int wr = wave / WAVES_N, wc = wave % WAVES_N;
  const int sr = t >> 2, sc = t & 3;
  const int frow = lane & 15, fk = (lane >> 4) * 8;

  f32x4 acc[MF][NF] = {};

  for (int k0 = 0; k0 < K; k0 += BK) {
#pragma unroll
    for (int qi = 0; qi < AI; ++qi) {
      const long long ro = (long long)(bm0 + qi * 64 + sr) * lda + (k0 + sc * 8);
      __builtin_amdgcn_global_load_lds(
          (const __attribute__((address_space(1))) void*)(A + ro),
          (__attribute__((address_space(3))) void*)(Ash + qi * 2048 + wave * 512), 16, 0, 0);
      __builtin_amdgcn_global_load_lds(
          (const __attribute__((address_space(1))) void*)(A + ro + loA),
          (__attribute__((address_space(3))) void*)(Asl + qi * 2048 + wave * 512), 16, 0, 0);
    }
#pragma unroll
    for (int qi = 0; qi < BI; ++qi) {
      const long long ro = (long long)(bn0 + qi * 64 + sr) * ldb + (k0 + sc * 8);
      __builtin_amdgcn_global_load_lds(
          (const __attribute__((address_space(1))) void*)(B + ro),
          (__attribute__((address_space(3))) void*)(Bsh + qi * 2048 + wave * 512), 16, 0, 0);
      __builtin_amdgcn_global_load_lds(
          (const __attribute__((address_space(1))) void*)(B + ro + loB),
          (__attribute__((address_space(3))) void*)(Bsl + qi * 2048 + wave * 512), 16, 0, 0);
    }
    __syncthreads();
    bf16x8 afh[MF], afl[MF], bfh[NF], bfl[NF];
#pragma unroll
    for (int m = 0; m < MF; m++) {
      afh[m] = *(const bf16x8*)(Ash + (wr * WM + m * 16 + frow) * BK + fk);
      afl[m] = *(const bf16x8*)(Asl + (wr * WM + m * 16 + frow) * BK + fk);
    }
#pragma unroll
    for (int n = 0; n < NF; n++) {
      bfh[n] = *(const bf16x8*)(Bsh + (wc * WN + n * 16 + frow) * BK + fk);
      bfl[n] = *(const bf16x8*)(Bsl + (wc * WN + n * 16 + frow) * BK + fk);
    }
#pragma unroll
    for (int m = 0; m < MF; m++)
#pragma unroll
      for (int n = 0; n < NF; n++) {
        acc[m][n] = __builtin_amdgcn_mfma_f32_16x16x32_bf16(afh[m], bfh[n], acc[m][n], 0, 0, 0);
        acc[m][n] = __builtin_amdgcn_mfma_f32_16x16x32_bf16(afl[m], bfh[n], acc[m][n], 0, 0, 0);
        acc[m][n] = __builtin_amdgcn_mfma_f32_16x16x32_bf16(afh[m], bfl[n], acc[m][n], 0, 0, 0);
      }
    __syncthreads();
  }

#pragma unroll
  for (int m = 0; m < MF; m++) {
#pragma unroll
    for (int n = 0; n < NF; n++) {
      const int row0 = bm0 + wr * WM + m * 16 + (lane >> 4) * 4;
      const int col = bn0 + wc * WN + n * 16 + (lane & 15);
#pragma unroll
      for (int r = 0; r < 4; r++) {
        const float v = acc[m][n][r] * scale;
        const long long i = row0 + r;
        if (EPI == EPI_F32) {
          (((float*)Cv) + z * sCz)[i * (long long)ldc + col] = v;
        } else if (EPI == EPI_SPLIT) {
          bf16* base = ((bf16*)Cv) + z * sCz;
          const long long ih = i * (long long)(2 * ldc) + col;
          bf16 h = (bf16)v;
          base[ih] = h;
          base[ih + ldc] = (bf16)(v - (float)h);
        } else if (EPI == EPI_GELUSPLIT) {
          float u = v + bias[col];
          float gl = 0.5f * u * (1.0f + erff(u * 0.7071067811865476f));
          const long long ih = i * (long long)(2 * ldc) + col;
          bf16 h = (bf16)gl;
          ((bf16*)Cv)[ih] = h;
          ((bf16*)Cv)[ih + ldc] = (bf16)(gl - (float)h);
        } else {  // EPI_RESID
          float* xp = ((float*)Cv) + i * ldc + col;
          *xp = *xp + v + bias[col];
        }
      }
    }
  }
}

// ---------------------------------------------------------------------------
// Barrier-free direct-register S-GEMM: S_h(i,j) = q_h(i).k_h(j), K=64.
// No LDS, no __syncthreads: waves load fragments straight from L2-resident
// Qs/Ks, 96 MFMAs, write to S[i_local][h][j]. grid (STRIPE/128, 17, 8).
// ---------------------------------------------------------------------------
__global__ __launch_bounds__(256)
void s_gemm_direct(const bf16* __restrict__ Qs, const bf16* __restrict__ Ks,
                   float* __restrict__ S)
{
  const int h = blockIdx.z;
  const int bm0 = blockIdx.x * 128;   // stripe-local row
  const int bn0 = blockIdx.y * 128;
  const int t = threadIdx.x;
  const int wave = t >> 6, lane = t & 63;
  const int wr = wave >> 1, wc = wave & 1;   // 2x2 waves, 64x64 each
  const int frow = lane & 15, fk = (lane >> 4) * 8;

  // A fragments (held): rows bm0+wr*64+m*16+frow, k = kk*32 + fk
  bf16x8 ah[4][2], al[4][2];
#pragma unroll
  for (int m = 0; m < 4; m++)
#pragma unroll
    for (int kk = 0; kk < 2; kk++) {
      const bf16* ap = Qs + (long long)(bm0 + wr * 64 + m * 16 + frow) * 1024
                     + h * 64 + kk * 32 + fk;
      ah[m][kk] = *(const bf16x8*)(ap);
      al[m][kk] = *(const bf16x8*)(ap + 512);
    }

  f32x4 acc[4][4] = {};
#pragma unroll
  for (int n = 0; n < 4; n++) {
    bf16x8 bh[2], bl[2];
#pragma unroll
    for (int kk = 0; kk < 2; kk++) {
      const bf16* bp = Ks + (long long)(bn0 + wc * 64 + n * 16 + frow) * 1024
                     + h * 64 + kk * 32 + fk;
      bh[kk] = *(const bf16x8*)(bp);
      bl[kk] = *(const bf16x8*)(bp + 512);
    }
#pragma unroll
    for (int m = 0; m < 4; m++)
#pragma unroll
      for (int kk = 0; kk < 2; kk++) {
        acc[m][n] = __builtin_amdgcn_mfma_f32_16x16x32_bf16(ah[m][kk], bh[kk], acc[m][n], 0, 0, 0);
        acc[m][n] = __builtin_amdgcn_mfma_f32_16x16x32_bf16(al[m][kk], bh[kk], acc[m][n], 0, 0, 0);
        acc[m][n] = __builtin_amdgcn_mfma_f32_16x16x32_bf16(ah[m][kk], bl[kk], acc[m][n], 0, 0, 0);
      }
  }

  // write S[row_local][h][j]
#pragma unroll
  for (int m = 0; m < 4; m++) {
#pragma unroll
    for (int n = 0; n < 4; n++) {
      const int row0 = bm0 + wr * 64 + m * 16 + (lane >> 4) * 4;
      const int col = bn0 + wc * 64 + n * 16 + (lane & 15);
#pragma unroll
      for (int r = 0; r < 4; r++)
        S[(long long)(row0 + r) * (NHEADS * NJP) + h * NJP + col] = acc[m][n][r];
    }
  }
}

// ---------------------------------------------------------------------------
// LayerNorm -> split bf16 (hi | lo), row stride 1024
// ---------------------------------------------------------------------------
__global__ __launch_bounds__(256)
void ln_kernel(const float* __restrict__ x, const float* __restrict__ g,
               const float* __restrict__ b, bf16* __restrict__ out)
{
  const int row = blockIdx.x * 4 + (threadIdx.x >> 6);
  const int lane = threadIdx.x & 63;
  const float* xr = x + (long long)row * NDIM;
  float4 a0 = ((const float4*)xr)[lane];
  float4 a1 = ((const float4*)xr)[lane + 64];
  float s = a0.x + a0.y + a0.z + a0.w + a1.x + a1.y + a1.z + a1.w;
  float ss = a0.x * a0.x + a0.y * a0.y + a0.z * a0.z + a0.w * a0.w
           + a1.x * a1.x + a1.y * a1.y + a1.z * a1.z + a1.w * a1.w;
#pragma unroll
  for (int d = 1; d < 64; d <<= 1) {
    s += __shfl_xor(s, d, 64);
    ss += __shfl_xor(ss, d, 64);
  }
  const float mean = s * (1.0f / NDIM);
  const float var = ss * (1.0f / NDIM) - mean * mean;
  const float rs = rsqrtf(var + 1e-5f);
  float4 g0 = ((const float4*)g)[lane], g1 = ((const float4*)g)[lane + 64];
  float4 b0 = ((const float4*)b)[lane], b1 = ((const float4*)b)[lane + 64];
  bf16* orow = out + (long long)row * (2 * NDIM);
  float y[8] = {
    (a0.x - mean) * rs * g0.x + b0.x, (a0.y - mean) * rs * g0.y + b0.y,
    (a0.z - mean) * rs * g0.z + b0.z, (a0.w - mean) * rs * g0.w + b0.w,
    (a1.x - mean) * rs * g1.x + b1.x, (a1.y - mean) * rs * g1.y + b1.y,
    (a1.z - mean) * rs * g1.z + b1.z, (a1.w - mean) * rs * g1.w + b1.w };
  bf16x4 h0, h1, l0, l1;
#pragma unroll
  for (int j = 0; j < 4; j++) {
    bf16 h = (bf16)y[j];      h0[j] = h;  l0[j] = (bf16)(y[j] - (float)h);
    bf16 h2 = (bf16)y[4 + j]; h1[j] = h2; l1[j] = (bf16)(y[4 + j] - (float)h2);
  }
  *(bf16x4*)(orow + lane * 4) = h0;
  *(bf16x4*)(orow + 256 + lane * 4) = h1;
  *(bf16x4*)(orow + 512 + lane * 4) = l0;
  *(bf16x4*)(orow + 768 + lane * 4) = l1;
}

// ---------------------------------------------------------------------------
// Ks[b][j][c]=hi, [c+512]=lo from kv k-part + mem_k; zero pad rows
// ---------------------------------------------------------------------------
__global__ __launch_bounds__(256)
void build_ks(const float* __restrict__ kv, const float* __restrict__ mem_k_l,
              bf16* __restrict__ Ks)
{
  const long long idx = (long long)blockIdx.x * 256 + threadIdx.x;  // [b][j][c]
  const int c = (int)(idx & 511);
  const int j = (int)((idx >> 9) % NJP);
  const int bb = (int)(idx / ((long long)NJP * NDIM));
  const int h = c >> 6, d = c & 63;
  float kval;
  if (j < NMEM) kval = mem_k_l[(h * NMEM + j) * DHEAD + d];
  else if (j < NJ) kval = kv[(long long)(bb * NSEQ + (j - NMEM)) * (2 * NDIM) + c];
  else kval = 0.f;
  bf16 hv = (bf16)kval;
  const long long ro = ((long long)bb * NJP + j) * (2 * NDIM) + c;
  Ks[ro] = hv;
  Ks[ro + NDIM] = (bf16)(kval - (float)hv);
}

// ---------------------------------------------------------------------------
// Fused mix + bias + top-8 + softmax + sparse PV gather, 2-phase LDS:
// stage heads 0-3 (34.8 KB), accumulate into v[34] regs, restage heads 4-7,
// finish. 512 thr = 8 waves (one per output head); blockIdx.x = stripe-local
// row. Branchless insertion, values-only butterfly, ballot recovery.
// ---------------------------------------------------------------------------
__global__ __launch_bounds__(512)
void mix_topk_gather(const float* __restrict__ S, const float* __restrict__ kv,
                     const float* __restrict__ mem_v_l, const float* __restrict__ pp,
                     const float* __restrict__ table, bf16* __restrict__ obufs,
                     int b, int i0)
{
  __shared__ float sm[4 * NJP];  // 34816 B
  const int il = blockIdx.x;
  const int i = i0 + il;
  const int k = threadIdx.x >> 6;
  const int lane = threadIdx.x & 63;
  const float* srow = S + (long long)il * (NHEADS * NJP);

  float pk[8];
#pragma unroll
  for (int h = 0; h < 8; h++) pk[h] = pp[h * 8 + k];

  float v[34];

  // ---- phase A: heads 0..3 ----
  {
    const float4* src = (const float4*)srow;
    float4* dst = (float4*)sm;
    for (int t = threadIdx.x; t < NJP; t += 512) dst[t] = src[t];
  }
  __syncthreads();
#pragma unroll
  for (int t = 0; t < 8; t++) {
    const int j0 = 256 * t + 4 * lane;
    const float* tb = table + (j0 - i + 2047) * 8 + k;
    float4 a;
    a.x = tb[0]; a.y = tb[8]; a.z = tb[16]; a.w = tb[24];
#pragma unroll
    for (int h = 0; h < 4; h++) {
      const float4 s4 = *(const float4*)(sm + h * NJP + j0);
      a.x = fmaf(s4.x, pk[h], a.x);
      a.y = fmaf(s4.y, pk[h], a.y);
      a.z = fmaf(s4.z, pk[h], a.z);
      a.w = fmaf(s4.w, pk[h], a.w);
    }
    v[t * 4 + 0] = a.x; v[t * 4 + 1] = a.y; v[t * 4 + 2] = a.z; v[t * 4 + 3] = a.w;
  }
  {
    const int j0 = 2048 + 2 * lane;
    const int jc = j0 < 2062 ? j0 : 2062;
    const float* tb = table + (jc - i + 2047) * 8 + k;
    float ax = tb[0], ay = tb[8];
#pragma unroll
    for (int h = 0; h < 4; h++) {
      const float2 s2 = *(const float2*)(sm + h * NJP + j0);
      ax = fmaf(s2.x, pk[h], ax);
      ay = fmaf(s2.y, pk[h], ay);
    }
    v[32] = ax; v[33] = ay;
  }
  __syncthreads();  // done reading phase-A sm

  // ---- phase B: heads 4..7 ----
  {
    const float4* src = (const float4*)(srow + 4 * NJP);
    float4* dst = (float4*)sm;
    for (int t = threadIdx.x; t < NJP; t += 512) dst[t] = src[t];
  }
  __syncthreads();

  float t8[8];
#pragma unroll
  for (int m = 0; m < 8; m++) t8[m] = -3.0e38f;

#pragma unroll
  for (int t = 0; t < 8; t++) {
    const int j0 = 256 * t + 4 * lane;
    float4 a;
    a.x = v[t * 4 + 0]; a.y = v[t * 4 + 1]; a.z = v[t * 4 + 2]; a.w = v[t * 4 + 3];
#pragma unroll
    for (int h = 4; h < 8; h++) {
      const float4 s4 = *(const float4*)(sm + (h - 4) * NJP + j0);
      a.x = fmaf(s4.x, pk[h], a.x);
      a.y = fmaf(s4.y, pk[h], a.y);
      a.z = fmaf(s4.z, pk[h], a.z);
      a.w = fmaf(s4.w, pk[h], a.w);
    }
    v[t * 4 + 0] = a.x; v[t * 4 + 1] = a.y; v[t * 4 + 2] = a.z; v[t * 4 + 3] = a.w;
#pragma unroll
    for (int e = 0; e < 4; e++) {
      float x = v[t * 4 + e];
#pragma unroll
      for (int m = 0; m < 8; m++) {
        const float hi = fmaxf(t8[m], x);
        x = fminf(t8[m], x);
        t8[m] = hi;
      }
    }
  }
  {
    const int j0 = 2048 + 2 * lane;
    float ax = v[32], ay = v[33];
#pragma unroll
    for (int h = 4; h < 8; h++) {
      const float2 s2 = *(const float2*)(sm + (h - 4) * NJP + j0);
      ax = fmaf(s2.x, pk[h], ax);
      ay = fmaf(s2.y, pk[h], ay);
    }
    v[32] = (j0 < NJ) ? ax : -1e30f;
    v[33] = (j0 + 1 < NJ) ? ay : -1e30f;
#pragma unroll
    for (int e = 32; e < 34; e++) {
      float x = v[e];
#pragma unroll
      for (int m = 0; m < 8; m++) {
        const float hi = fmaxf(t8[m], x);
        x = fminf(t8[m], x);
        t8[m] = hi;
      }
    }
  }

  // values-only butterfly: global top-8 (sorted desc) in every lane
#pragma unroll
  for (int d = 1; d < 64; d <<= 1) {
    float o[8], m8[8];
#pragma unroll
    for (int m = 0; m < 8; m++) o[m] = __shfl_xor(t8[m], d, 64);
#pragma unroll
    for (int m = 0; m < 8; m++) m8[m] = fmaxf(t8[m], o[7 - m]);
#define CX(a, bq) { float hi = fmaxf(m8[a], m8[bq]); float lo = fminf(m8[a], m8[bq]); m8[a] = hi; m8[bq] = lo; }
    CX(0, 4) CX(1, 5) CX(2, 6) CX(3, 7)
    CX(0, 2) CX(1, 3) CX(4, 6) CX(5, 7)
    CX(0, 1) CX(2, 3) CX(4, 5) CX(6, 7)
#undef CX
#pragma unroll
    for (int m = 0; m < 8; m++) t8[m] = m8[m];
  }
  const float mx = t8[0];
  const float thr = t8[7];
  float denom = 0.f;
#pragma unroll
  for (int m = 0; m < 8; m++) denom += expf(t8[m] - mx);
  const float inv = 1.0f / denom;

  // index recovery + gather
  float acc = 0.f;
#pragma unroll
  for (int t = 0; t < 8; t++) {
#pragma unroll
    for (int e = 0; e < 4; e++) {
      unsigned long long mball = __ballot(v[t * 4 + e] >= thr);
      while (mball) {
        const int l = __builtin_ctzll(mball);
        mball &= mball - 1;
        const int jj = 256 * t + 4 * l + e;
        const float sv = __shfl(v[t * 4 + e], l);
        const float w = expf(sv - mx) * inv;
        const float vv = (jj < NMEM)
            ? mem_v_l[(k * NMEM + jj) * DHEAD + lane]
            : kv[(long long)(b * NSEQ + (jj - NMEM)) * (2 * NDIM) + NDIM + k * DHEAD + lane];
        acc = fmaf(w, vv, acc);
      }
    }
  }
#pragma unroll
  for (int e = 0; e < 2; e++) {
    unsigned long long mball = __ballot(v[32 + e] >= thr);
    while (mball) {
      const int l = __builtin_ctzll(mball);
      mball &= mball - 1;
      const int jj = 2048 + 2 * l + e;
      const float sv = __shfl(v[32 + e], l);
      const float w = expf(sv - mx) * inv;
      const float vv = (jj < NMEM)
          ? mem_v_l[(k * NMEM + jj) * DHEAD + lane]
          : kv[(long long)(b * NSEQ + (jj - NMEM)) * (2 * NDIM) + NDIM + k * DHEAD + lane];
      acc = fmaf(w, vv, acc);
    }
  }

  const long long orow = (long long)(b * NSEQ + i) * (2 * NDIM) + k * DHEAD + lane;
  bf16 h = (bf16)acc;
  obufs[orow] = h;
  obufs[orow + NDIM] = (bf16)(acc - (float)h);
}

// ---------------------------------------------------------------------------
// fp32 weight (R x C row-major) -> split-transposed bf16 (C x 2R)
// ---------------------------------------------------------------------------
__global__ __launch_bounds__(256)
void transpose_split(const float* __restrict__ in, bf16* __restrict__ out,
                     int R, int C)
{
  const long long idx = (long long)blockIdx.x * 256 + threadIdx.x;
  if (idx >= (long long)R * C) return;
  const int r = (int)(idx / C);
  const int c = (int)(idx % C);
  float v = in[idx];
  bf16 h = (bf16)v;
  out[(long long)c * (2 * R) + r] = h;
  out[(long long)c * (2 * R) + R + r] = (bf16)(v - (float)h);
}

// ---------------------------------------------------------------------------
// T5 bias table; bucket boundaries are exact via log2
// ---------------------------------------------------------------------------
__global__ __launch_bounds__(256)
void build_bias(const float* __restrict__ rel_emb, float* __restrict__ table)
{
  const int idx = blockIdx.x * 256 + threadIdx.x;
  if (idx >= 4111 * 8) return;
  const int h = idx & 7;
  const int rel = (idx >> 3) - 2047;  // rel = j - i
  const int n = -rel;
  const int ret = (n < 0) ? 16 : 0;
  const int na = n < 0 ? -n : n;
  int bucket;
  if (na < 8) {
    bucket = ret + na;
  } else {
    int vl = 8 + (int)(log2((double)na * 0.125) * 2.0);
    vl = vl < 15 ? vl : 15;
    bucket = ret + vl;
  }
  table[idx] = rel_emb[bucket * 8 + h];
}

// ---------------------------------------------------------------------------
extern "C" void kernel_launch(void* const* d_in, const int* in_sizes, int n_in,
                              void* d_out, int out_size, void* d_ws, size_t ws_size,
                              hipStream_t stream)
{
  const float* x_in    = (const float*)d_in[0];
  const float* ln1_g   = (const float*)d_in[1];
  const float* ln1_b   = (const float*)d_in[2];
  const float* Wq      = (const float*)d_in[3];
  const float* Wkv     = (const float*)d_in[4];
  const float* Wo      = (const float*)d_in[5];
  const float* bo      = (const float*)d_in[6];
  const float* pre_proj= (const float*)d_in[7];
  const float* mem_k   = (const float*)d_in[8];
  const float* mem_v   = (const float*)d_in[9];
  const float* ln2_g   = (const float*)d_in[10];
  const float* ln2_b   = (const float*)d_in[11];
  const float* W1      = (const float*)d_in[12];
  const float* b1      = (const float*)d_in[13];
  const float* W2      = (const float*)d_in[14];
  const float* b2      = (const float*)d_in[15];
  const float* rel_emb = (const float*)d_in[16];

  char* p = (char*)d_ws;
  auto alloc = [&](size_t bytes) -> char* {
    char* r = p;
    p += (bytes + 255) & ~(size_t)255;
    return r;
  };

  // ~164 MB total with phase-disjoint aliasing
  float* x    = (float*)alloc((size_t)NROWS * NDIM * 4);          // 8.4 MB
  char*  RA   = alloc((size_t)NROWS * 2 * NDIM * 2);              // 8.4 MB: hs | obufs
  bf16*  hs    = (bf16*)RA;
  bf16*  obufs = (bf16*)RA;
  char*  RB   = alloc((size_t)NROWS * 2 * NFF * 2);               // 33.6 MB: (Qs+Ks) | tbufs
  bf16*  Qs    = (bf16*)RB;                                       // 8.4 MB
  bf16*  Ks    = (bf16*)(RB + (size_t)NROWS * 2 * NDIM * 2);      // 8.9 MB
  bf16*  tbufs = (bf16*)RB;
  float* kv   = (float*)alloc((size_t)NROWS * 2 * NDIM * 4);      // 16.8 MB
  float* S    = (float*)alloc((size_t)STRIPE * NHEADS * NJP * 4); // 71.3 MB, [i_local][h][j]
  bf16*  WqT  = (bf16*)alloc((size_t)2 * NDIM * 2 * NDIM * 2);
  bf16*  WkvT = (bf16*)alloc((size_t)2 * 2 * NDIM * 2 * NDIM * 2);
  bf16*  WoT  = (bf16*)alloc((size_t)2 * NDIM * 2 * NDIM * 2);
  bf16*  W1T  = (bf16*)alloc((size_t)2 * NFF * 2 * NDIM * 2);
  bf16*  W2T  = (bf16*)alloc((size_t)2 * NDIM * 2 * NFF * 2);
  float* table= (float*)alloc((size_t)4111 * 8 * 4);

  // ---- prep ----
  hipMemcpyAsync(x, x_in, (size_t)NROWS * NDIM * 4, hipMemcpyDeviceToDevice, stream);
  build_bias<<<(4111 * 8 + 255) / 256, 256, 0, stream>>>(rel_emb, table);
  for (int l = 0; l < 2; l++) {
    transpose_split<<<(NDIM * NDIM + 255) / 256, 256, 0, stream>>>(
        Wq + (size_t)l * NDIM * NDIM, WqT + (size_t)l * NDIM * 2 * NDIM, NDIM, NDIM);
    transpose_split<<<(2 * NDIM * NDIM + 255) / 256, 256, 0, stream>>>(
        Wkv + (size_t)l * NDIM * 2 * NDIM, WkvT + (size_t)l * 2 * NDIM * 2 * NDIM, NDIM, 2 * NDIM);
    transpose_split<<<(NDIM * NDIM + 255) / 256, 256, 0, stream>>>(
        Wo + (size_t)l * NDIM * NDIM, WoT + (size_t)l * NDIM * 2 * NDIM, NDIM, NDIM);
    transpose_split<<<(NDIM * NFF + 255) / 256, 256, 0, stream>>>(
        W1 + (size_t)l * NDIM * NFF, W1T + (size_t)l * NFF * 2 * NDIM, NDIM, NFF);
    transpose_split<<<(NFF * NDIM + 255) / 256, 256, 0, stream>>>(
        W2 + (size_t)l * NFF * NDIM, W2T + (size_t)l * NDIM * 2 * NFF, NFF, NDIM);
  }

  // ---- layers ----
  for (int l = 0; l < 2; l++) {
    const bf16* WqT_l  = WqT + (size_t)l * NDIM * 2 * NDIM;
    const bf16* WkvT_l = WkvT + (size_t)l * 2 * NDIM * 2 * NDIM;
    const bf16* WoT_l  = WoT + (size_t)l * NDIM * 2 * NDIM;
    const bf16* W1T_l  = W1T + (size_t)l * NFF * 2 * NDIM;
    const bf16* W2T_l  = W2T + (size_t)l * NDIM * 2 * NFF;
    const float* mem_v_l = mem_v + (size_t)l * NHEADS * NMEM * DHEAD;

    ln_kernel<<<NROWS / 4, 256, 0, stream>>>(x, ln1_g + l * NDIM, ln1_b + l * NDIM, hs);
    gemm_split<128, 128, 2, 2, EPI_SPLIT><<<dim3(NROWS / 128, NDIM / 128, 1), 256, 0, stream>>>(
        hs, WqT_l, Qs, nullptr, NDIM, 2 * NDIM, 2 * NDIM, NDIM, NDIM, NDIM, 0, 0, 0, 0.125f);
    gemm_split<128, 128, 2, 2, EPI_F32><<<dim3(NROWS / 128, 2 * NDIM / 128, 1), 256, 0, stream>>>(
        hs, WkvT_l, kv, nullptr, NDIM, 2 * NDIM, 2 * NDIM, 2 * NDIM, NDIM, NDIM, 0, 0, 0, 1.0f);
    build_ks<<<(int)(((long long)NB * NJP * NDIM) / 256), 256, 0, stream>>>(
        kv, mem_k + (size_t)l * NHEADS * NMEM * DHEAD, Ks);

    for (int b = 0; b < NB; b++) {
      for (int i0 = 0; i0 < NSEQ; i0 += STRIPE) {
        s_gemm_direct<<<dim3(STRIPE / 128, NJP / 128, NHEADS), 256, 0, stream>>>(
            Qs + ((long long)b * NSEQ + i0) * 1024,
            Ks + (long long)b * NJP * 1024, S);
        mix_topk_gather<<<STRIPE, 512, 0, stream>>>(
            S, kv, mem_v_l, pre_proj + l * 64, table, obufs, b, i0);
      }
    }

    gemm_split<128, 128, 2, 2, EPI_RESID><<<dim3(NROWS / 128, NDIM / 128, 1), 256, 0, stream>>>(
        obufs, WoT_l, x, bo + l * NDIM, NDIM, 2 * NDIM, 2 * NDIM, NDIM, NDIM, NDIM, 0, 0, 0, 1.0f);

    ln_kernel<<<NROWS / 4, 256, 0, stream>>>(x, ln2_g + l * NDIM, ln2_b + l * NDIM, hs);
    gemm_split<128, 128, 2, 2, EPI_GELUSPLIT><<<dim3(NROWS / 128, NFF / 128, 1), 256, 0, stream>>>(
        hs, W1T_l, tbufs, b1 + l * NFF, NDIM, 2 * NDIM, 2 * NDIM, NFF, NDIM, NDIM, 0, 0, 0, 1.0f);
    gemm_split<128, 128, 2, 2, EPI_RESID><<<dim3(NROWS / 128, NDIM / 128, 1), 256, 0, stream>>>(
        tbufs, W2T_l, x, b2 + l * NDIM, NFF, 2 * NFF, 2 * NFF, NDIM, NFF, NFF, 0, 0, 0, 1.0f);
  }

  hipMemcpyAsync(d_out, x, (size_t)out_size * 4, hipMemcpyDeviceToDevice, stream);
}

// Round 9
// 947.078 us; speedup vs baseline: 1.1934x; 1.1934x over previous
//
#include <hip/hip_runtime.h>
#include <cmath>

typedef __bf16 bf16;
typedef __attribute__((ext_vector_type(8))) __bf16 bf16x8;
typedef __attribute__((ext_vector_type(4))) __bf16 bf16x4;
typedef __attribute__((ext_vector_type(4))) float f32x4;

#define NB 2
#define NSEQ 2048
#define NDIM 512
#define NHEADS 8
#define DHEAD 64
#define NMEM 16
#define NJ 2064
#define NJP 2176        // 17*128
#define NFF 2048
#define NROWS (NB*NSEQ) // 4096

enum { EPI_QKV = 0, EPI_GELUSPLIT = 1, EPI_RESID = 2 };

// ---------------------------------------------------------------------------
// Split-precision GEMM with double-buffered global_load_lds prefetch.
// fp32 operands stored as bf16 (hi,lo): hi at col c, lo at col c+loA/loB.
// C = Ah*Bh + Al*Bh + Ah*Bl, fp32 accum.  Per K-step: issue next-tile stage,
// then ds_read+MFMA current, then one barrier (T3-minimal pipeline).
// ---------------------------------------------------------------------------
template<int BM, int BN, int WAVES_M, int WAVES_N, int EPI>
__global__ __launch_bounds__(256)
void gemm_split(const bf16* __restrict__ A, const bf16* __restrict__ B,
                void* __restrict__ Cv, const float* __restrict__ bias,
                void* __restrict__ Cv2,
                int K, int lda, int ldb, int ldc, int loA, int loB)
{
  constexpr int BK = 32;
  constexpr int WM = BM / WAVES_M;
  constexpr int WN = BN / WAVES_N;
  constexpr int MF = WM / 16;
  constexpr int NF = WN / 16;
  constexpr int AI = (BM * BK * 2) / 4096;
  constexpr int BI = (BN * BK * 2) / 4096;
  __shared__ bf16 Ash[2][BM * BK];
  __shared__ bf16 Asl[2][BM * BK];
  __shared__ bf16 Bsh[2][BN * BK];
  __shared__ bf16 Bsl[2][BN * BK];

  const int bm0 = blockIdx.x * BM;
  const int bn0 = blockIdx.y * BN;
  const int t = threadIdx.x;
  const int wave = t >> 6, lane = t & 63;
  const int wr = wave / WAVES_N, wc = wave % WAVES_N;
  const int sr = t >> 2, sc = t & 3;
  const int frow = lane & 15, fk = (lane >> 4) * 8;

  auto stage = [&](int buf, int k0) {
#pragma unroll
    for (int qi = 0; qi < AI; ++qi) {
      const long long ro = (long long)(bm0 + qi * 64 + sr) * lda + (k0 + sc * 8);
      __builtin_amdgcn_global_load_lds(
          (const __attribute__((address_space(1))) void*)(A + ro),
          (__attribute__((address_space(3))) void*)(&Ash[buf][qi * 2048 + wave * 512]), 16, 0, 0);
      __builtin_amdgcn_global_load_lds(
          (const __attribute__((address_space(1))) void*)(A + ro + loA),
          (__attribute__((address_space(3))) void*)(&Asl[buf][qi * 2048 + wave * 512]), 16, 0, 0);
    }
#pragma unroll
    for (int qi = 0; qi < BI; ++qi) {
      const long long ro = (long long)(bn0 + qi * 64 + sr) * ldb + (k0 + sc * 8);
      __builtin_amdgcn_global_load_lds(
          (const __attribute__((address_space(1))) void*)(B + ro),
          (__attribute__((address_space(3))) void*)(&Bsh[buf][qi * 2048 + wave * 512]), 16, 0, 0);
      __builtin_amdgcn_global_load_lds(
          (const __attribute__((address_space(1))) void*)(B + ro + loB),
          (__attribute__((address_space(3))) void*)(&Bsl[buf][qi * 2048 + wave * 512]), 16, 0, 0);
    }
  };

  f32x4 acc[MF][NF] = {};

  stage(0, 0);
  __syncthreads();
  int cur = 0;
  for (int k0 = 0; k0 < K; k0 += BK) {
    if (k0 + BK < K) stage(cur ^ 1, k0 + BK);   // prefetch next tile (async)
    bf16x8 afh[MF], afl[MF], bfh[NF], bfl[NF];
#pragma unroll
    for (int m = 0; m < MF; m++) {
      afh[m] = *(const bf16x8*)(&Ash[cur][(wr * WM + m * 16 + frow) * BK + fk]);
      afl[m] = *(const bf16x8*)(&Asl[cur][(wr * WM + m * 16 + frow) * BK + fk]);
    }
#pragma unroll
    for (int n = 0; n < NF; n++) {
      bfh[n] = *(const bf16x8*)(&Bsh[cur][(wc * WN + n * 16 + frow) * BK + fk]);
      bfl[n] = *(const bf16x8*)(&Bsl[cur][(wc * WN + n * 16 + frow) * BK + fk]);
    }
#pragma unroll
    for (int m = 0; m < MF; m++)
#pragma unroll
      for (int n = 0; n < NF; n++) {
        acc[m][n] = __builtin_amdgcn_mfma_f32_16x16x32_bf16(afh[m], bfh[n], acc[m][n], 0, 0, 0);
        acc[m][n] = __builtin_amdgcn_mfma_f32_16x16x32_bf16(afl[m], bfh[n], acc[m][n], 0, 0, 0);
        acc[m][n] = __builtin_amdgcn_mfma_f32_16x16x32_bf16(afh[m], bfl[n], acc[m][n], 0, 0, 0);
      }
    __syncthreads();   // drains prefetch (vmcnt) + all waves done reading cur
    cur ^= 1;
  }

  // C/D layout: col=lane&15, row=(lane>>4)*4+reg
#pragma unroll
  for (int m = 0; m < MF; m++) {
#pragma unroll
    for (int n = 0; n < NF; n++) {
      const int row0 = bm0 + wr * WM + m * 16 + (lane >> 4) * 4;
      const int col = bn0 + wc * WN + n * 16 + (lane & 15);
#pragma unroll
      for (int r = 0; r < 4; r++) {
        const float v = acc[m][n][r];
        const long long i = row0 + r;
        if (EPI == EPI_QKV) {
          if (col < NDIM) {        // Qs: split write with 0.125 scale folded
            const float vq = v * 0.125f;
            bf16* base = (bf16*)Cv;
            const long long ih = i * (long long)(2 * NDIM) + col;
            bf16 h = (bf16)vq;
            base[ih] = h;
            base[ih + NDIM] = (bf16)(vq - (float)h);
          } else {                 // kv: fp32
            ((float*)Cv2)[i * (long long)(2 * NDIM) + (col - NDIM)] = v;
          }
        } else if (EPI == EPI_GELUSPLIT) {
          float u = v + bias[col];
          float gl = 0.5f * u * (1.0f + erff(u * 0.7071067811865476f));
          const long long ih = i * (long long)(2 * ldc) + col;
          bf16 h = (bf16)gl;
          ((bf16*)Cv)[ih] = h;
          ((bf16*)Cv)[ih + ldc] = (bf16)(gl - (float)h);
        } else {  // EPI_RESID
          float* xp = ((float*)Cv) + i * ldc + col;
          *xp = *xp + v + bias[col];
        }
      }
    }
  }
}

// ---------------------------------------------------------------------------
// Barrier-free direct-register S-GEMM: S_h(i,j) = q_h(i).k_h(j), K=64.
// grid (NSEQ/128, 17, 8); writes S[i][h][j].
// ---------------------------------------------------------------------------
__global__ __launch_bounds__(256)
void s_gemm_direct(const bf16* __restrict__ Qs, const bf16* __restrict__ Ks,
                   float* __restrict__ S)
{
  const int h = blockIdx.z;
  const int bm0 = blockIdx.x * 128;
  const int bn0 = blockIdx.y * 128;
  const int t = threadIdx.x;
  const int wave = t >> 6, lane = t & 63;
  const int wr = wave >> 1, wc = wave & 1;
  const int frow = lane & 15, fk = (lane >> 4) * 8;

  bf16x8 ah[4][2], al[4][2];
#pragma unroll
  for (int m = 0; m < 4; m++)
#pragma unroll
    for (int kk = 0; kk < 2; kk++) {
      const bf16* ap = Qs + (long long)(bm0 + wr * 64 + m * 16 + frow) * 1024
                     + h * 64 + kk * 32 + fk;
      ah[m][kk] = *(const bf16x8*)(ap);
      al[m][kk] = *(const bf16x8*)(ap + 512);
    }

  f32x4 acc[4][4] = {};
#pragma unroll
  for (int n = 0; n < 4; n++) {
    bf16x8 bh[2], bl[2];
#pragma unroll
    for (int kk = 0; kk < 2; kk++) {
      const bf16* bp = Ks + (long long)(bn0 + wc * 64 + n * 16 + frow) * 1024
                     + h * 64 + kk * 32 + fk;
      bh[kk] = *(const bf16x8*)(bp);
      bl[kk] = *(const bf16x8*)(bp + 512);
    }
#pragma unroll
    for (int m = 0; m < 4; m++)
#pragma unroll
      for (int kk = 0; kk < 2; kk++) {
        acc[m][n] = __builtin_amdgcn_mfma_f32_16x16x32_bf16(ah[m][kk], bh[kk], acc[m][n], 0, 0, 0);
        acc[m][n] = __builtin_amdgcn_mfma_f32_16x16x32_bf16(al[m][kk], bh[kk], acc[m][n], 0, 0, 0);
        acc[m][n] = __builtin_amdgcn_mfma_f32_16x16x32_bf16(ah[m][kk], bl[kk], acc[m][n], 0, 0, 0);
      }
  }

#pragma unroll
  for (int m = 0; m < 4; m++) {
#pragma unroll
    for (int n = 0; n < 4; n++) {
      const int row0 = bm0 + wr * 64 + m * 16 + (lane >> 4) * 4;
      const int col = bn0 + wc * 64 + n * 16 + (lane & 15);
#pragma unroll
      for (int r = 0; r < 4; r++)
        S[(long long)(row0 + r) * (NHEADS * NJP) + h * NJP + col] = acc[m][n][r];
    }
  }
}

// ---------------------------------------------------------------------------
// LayerNorm -> split bf16 (hi | lo), row stride 1024
// ---------------------------------------------------------------------------
__global__ __launch_bounds__(256)
void ln_kernel(const float* __restrict__ x, const float* __restrict__ g,
               const float* __restrict__ b, bf16* __restrict__ out)
{
  const int row = blockIdx.x * 4 + (threadIdx.x >> 6);
  const int lane = threadIdx.x & 63;
  const float* xr = x + (long long)row * NDIM;
  float4 a0 = ((const float4*)xr)[lane];
  float4 a1 = ((const float4*)xr)[lane + 64];
  float s = a0.x + a0.y + a0.z + a0.w + a1.x + a1.y + a1.z + a1.w;
  float ss = a0.x * a0.x + a0.y * a0.y + a0.z * a0.z + a0.w * a0.w
           + a1.x * a1.x + a1.y * a1.y + a1.z * a1.z + a1.w * a1.w;
#pragma unroll
  for (int d = 1; d < 64; d <<= 1) {
    s += __shfl_xor(s, d, 64);
    ss += __shfl_xor(ss, d, 64);
  }
  const float mean = s * (1.0f / NDIM);
  const float var = ss * (1.0f / NDIM) - mean * mean;
  const float rs = rsqrtf(var + 1e-5f);
  float4 g0 = ((const float4*)g)[lane], g1 = ((const float4*)g)[lane + 64];
  float4 b0 = ((const float4*)b)[lane], b1 = ((const float4*)b)[lane + 64];
  bf16* orow = out + (long long)row * (2 * NDIM);
  float y[8] = {
    (a0.x - mean) * rs * g0.x + b0.x, (a0.y - mean) * rs * g0.y + b0.y,
    (a0.z - mean) * rs * g0.z + b0.z, (a0.w - mean) * rs * g0.w + b0.w,
    (a1.x - mean) * rs * g1.x + b1.x, (a1.y - mean) * rs * g1.y + b1.y,
    (a1.z - mean) * rs * g1.z + b1.z, (a1.w - mean) * rs * g1.w + b1.w };
  bf16x4 h0, h1, l0, l1;
#pragma unroll
  for (int j = 0; j < 4; j++) {
    bf16 h = (bf16)y[j];      h0[j] = h;  l0[j] = (bf16)(y[j] - (float)h);
    bf16 h2 = (bf16)y[4 + j]; h1[j] = h2; l1[j] = (bf16)(y[4 + j] - (float)h2);
  }
  *(bf16x4*)(orow + lane * 4) = h0;
  *(bf16x4*)(orow + 256 + lane * 4) = h1;
  *(bf16x4*)(orow + 512 + lane * 4) = l0;
  *(bf16x4*)(orow + 768 + lane * 4) = l1;
}

// ---------------------------------------------------------------------------
// Ks[b][j][c]=hi, [c+512]=lo from kv k-part + mem_k; zero pad rows
// ---------------------------------------------------------------------------
__global__ __launch_bounds__(256)
void build_ks(const float* __restrict__ kv, const float* __restrict__ mem_k_l,
              bf16* __restrict__ Ks)
{
  const long long idx = (long long)blockIdx.x * 256 + threadIdx.x;
  const int c = (int)(idx & 511);
  const int j = (int)((idx >> 9) % NJP);
  const int bb = (int)(idx / ((long long)NJP * NDIM));
  const int h = c >> 6, d = c & 63;
  float kval;
  if (j < NMEM) kval = mem_k_l[(h * NMEM + j) * DHEAD + d];
  else if (j < NJ) kval = kv[(long long)(bb * NSEQ + (j - NMEM)) * (2 * NDIM) + c];
  else kval = 0.f;
  bf16 hv = (bf16)kval;
  const long long ro = ((long long)bb * NJP + j) * (2 * NDIM) + c;
  Ks[ro] = hv;
  Ks[ro + NDIM] = (bf16)(kval - (float)hv);
}

// ---------------------------------------------------------------------------
// Fused mix + bias + top-8 + softmax + sparse PV gather, 2-phase LDS
// (heads 0-3 then 4-7, 34.8 KB). 512 thr = 8 waves (one per output head).
// ---------------------------------------------------------------------------
__global__ __launch_bounds__(512)
void mix_topk_gather(const float* __restrict__ S, const float* __restrict__ kv,
                     const float* __restrict__ mem_v_l, const float* __restrict__ pp,
                     const float* __restrict__ table, bf16* __restrict__ obufs,
                     int b)
{
  __shared__ float sm[4 * NJP];  // 34816 B
  const int i = blockIdx.x;
  const int k = threadIdx.x >> 6;
  const int lane = threadIdx.x & 63;
  const float* srow = S + (long long)i * (NHEADS * NJP);

  float pk[8];
#pragma unroll
  for (int h = 0; h < 8; h++) pk[h] = pp[h * 8 + k];

  float v[34];

  // ---- phase A: heads 0..3 ----
  {
    const float4* src = (const float4*)srow;
    float4* dst = (float4*)sm;
    for (int t = threadIdx.x; t < NJP; t += 512) dst[t] = src[t];
  }
  __syncthreads();
#pragma unroll
  for (int t = 0; t < 8; t++) {
    const int j0 = 256 * t + 4 * lane;
    const float* tb = table + (j0 - i + 2047) * 8 + k;
    float4 a;
    a.x = tb[0]; a.y = tb[8]; a.z = tb[16]; a.w = tb[24];
#pragma unroll
    for (int h = 0; h < 4; h++) {
      const float4 s4 = *(const float4*)(sm + h * NJP + j0);
      a.x = fmaf(s4.x, pk[h], a.x);
      a.y = fmaf(s4.y, pk[h], a.y);
      a.z = fmaf(s4.z, pk[h], a.z);
      a.w = fmaf(s4.w, pk[h], a.w);
    }
    v[t * 4 + 0] = a.x; v[t * 4 + 1] = a.y; v[t * 4 + 2] = a.z; v[t * 4 + 3] = a.w;
  }
  {
    const int j0 = 2048 + 2 * lane;
    const int jc = j0 < 2062 ? j0 : 2062;
    const float* tb = table + (jc - i + 2047) * 8 + k;
    float ax = tb[0], ay = tb[8];
#pragma unroll
    for (int h = 0; h < 4; h++) {
      const float2 s2 = *(const float2*)(sm + h * NJP + j0);
      ax = fmaf(s2.x, pk[h], ax);
      ay = fmaf(s2.y, pk[h], ay);
    }
    v[32] = ax; v[33] = ay;
  }
  __syncthreads();

  // ---- phase B: heads 4..7 ----
  {
    const float4* src = (const float4*)(srow + 4 * NJP);
    float4* dst = (float4*)sm;
    for (int t = threadIdx.x; t < NJP; t += 512) dst[t] = src[t];
  }
  __syncthreads();

  float t8[8];
#pragma unroll
  for (int m = 0; m < 8; m++) t8[m] = -3.0e38f;

#pragma unroll
  for (int t = 0; t < 8; t++) {
    const int j0 = 256 * t + 4 * lane;
    float4 a;
    a.x = v[t * 4 + 0]; a.y = v[t * 4 + 1]; a.z = v[t * 4 + 2]; a.w = v[t * 4 + 3];
#pragma unroll
    for (int h = 4; h < 8; h++) {
      const float4 s4 = *(const float4*)(sm + (h - 4) * NJP + j0);
      a.x = fmaf(s4.x, pk[h], a.x);
      a.y = fmaf(s4.y, pk[h], a.y);
      a.z = fmaf(s4.z, pk[h], a.z);
      a.w = fmaf(s4.w, pk[h], a.w);
    }
    v[t * 4 + 0] = a.x; v[t * 4 + 1] = a.y; v[t * 4 + 2] = a.z; v[t * 4 + 3] = a.w;
#pragma unroll
    for (int e = 0; e < 4; e++) {
      float x = v[t * 4 + e];
#pragma unroll
      for (int m = 0; m < 8; m++) {
        const float hi = fmaxf(t8[m], x);
        x = fminf(t8[m], x);
        t8[m] = hi;
      }
    }
  }
  {
    const int j0 = 2048 + 2 * lane;
    float ax = v[32], ay = v[33];
#pragma unroll
    for (int h = 4; h < 8; h++) {
      const float2 s2 = *(const float2*)(sm + (h - 4) * NJP + j0);
      ax = fmaf(s2.x, pk[h], ax);
      ay = fmaf(s2.y, pk[h], ay);
    }
    v[32] = (j0 < NJ) ? ax : -1e30f;
    v[33] = (j0 + 1 < NJ) ? ay : -1e30f;
#pragma unroll
    for (int e = 32; e < 34; e++) {
      float x = v[e];
#pragma unroll
      for (int m = 0; m < 8; m++) {
        const float hi = fmaxf(t8[m], x);
        x = fminf(t8[m], x);
        t8[m] = hi;
      }
    }
  }

  // values-only butterfly: global top-8 (sorted desc) in every lane
#pragma unroll
  for (int d = 1; d < 64; d <<= 1) {
    float o[8], m8[8];
#pragma unroll
    for (int m = 0; m < 8; m++) o[m] = __shfl_xor(t8[m], d, 64);
#pragma unroll
    for (int m = 0; m < 8; m++) m8[m] = fmaxf(t8[m], o[7 - m]);
#define CX(a, bq) { float hi = fmaxf(m8[a], m8[bq]); float lo = fminf(m8[a], m8[bq]); m8[a] = hi; m8[bq] = lo; }
    CX(0, 4) CX(1, 5) CX(2, 6) CX(3, 7)
    CX(0, 2) CX(1, 3) CX(4, 6) CX(5, 7)
    CX(0, 1) CX(2, 3) CX(4, 5) CX(6, 7)
#undef CX
#pragma unroll
    for (int m = 0; m < 8; m++) t8[m] = m8[m];
  }
  const float mx = t8[0];
  const float thr = t8[7];
  float denom = 0.f;
#pragma unroll
  for (int m = 0; m < 8; m++) denom += expf(t8[m] - mx);
  const float inv = 1.0f / denom;

  float acc = 0.f;
#pragma unroll
  for (int t = 0; t < 8; t++) {
#pragma unroll
    for (int e = 0; e < 4; e++) {
      unsigned long long mball = __ballot(v[t * 4 + e] >= thr);
      while (mball) {
        const int l = __builtin_ctzll(mball);
        mball &= mball - 1;
        const int jj = 256 * t + 4 * l + e;
        const float sv = __shfl(v[t * 4 + e], l);
        const float w = expf(sv - mx) * inv;
        const float vv = (jj < NMEM)
            ? mem_v_l[(k * NMEM + jj) * DHEAD + lane]
            : kv[(long long)(b * NSEQ + (jj - NMEM)) * (2 * NDIM) + NDIM + k * DHEAD + lane];
        acc = fmaf(w, vv, acc);
      }
    }
  }
#pragma unroll
  for (int e = 0; e < 2; e++) {
    unsigned long long mball = __ballot(v[32 + e] >= thr);
    while (mball) {
      const int l = __builtin_ctzll(mball);
      mball &= mball - 1;
      const int jj = 2048 + 2 * l + e;
      const float sv = __shfl(v[32 + e], l);
      const float w = expf(sv - mx) * inv;
      const float vv = (jj < NMEM)
          ? mem_v_l[(k * NMEM + jj) * DHEAD + lane]
          : kv[(long long)(b * NSEQ + (jj - NMEM)) * (2 * NDIM) + NDIM + k * DHEAD + lane];
      acc = fmaf(w, vv, acc);
    }
  }

  const long long orow = (long long)(b * NSEQ + i) * (2 * NDIM) + k * DHEAD + lane;
  bf16 h = (bf16)acc;
  obufs[orow] = h;
  obufs[orow + NDIM] = (bf16)(acc - (float)h);
}

// ---------------------------------------------------------------------------
// fp32 weight (R x C row-major) -> split-transposed bf16 (C x 2R)
// ---------------------------------------------------------------------------
__global__ __launch_bounds__(256)
void transpose_split(const float* __restrict__ in, bf16* __restrict__ out,
                     int R, int C)
{
  const long long idx = (long long)blockIdx.x * 256 + threadIdx.x;
  if (idx >= (long long)R * C) return;
  const int r = (int)(idx / C);
  const int c = (int)(idx % C);
  float v = in[idx];
  bf16 h = (bf16)v;
  out[(long long)c * (2 * R) + r] = h;
  out[(long long)c * (2 * R) + R + r] = (bf16)(v - (float)h);
}

// ---------------------------------------------------------------------------
// T5 bias table; bucket boundaries are exact via log2
// ---------------------------------------------------------------------------
__global__ __launch_bounds__(256)
void build_bias(const float* __restrict__ rel_emb, float* __restrict__ table)
{
  const int idx = blockIdx.x * 256 + threadIdx.x;
  if (idx >= 4111 * 8) return;
  const int h = idx & 7;
  const int rel = (idx >> 3) - 2047;
  const int n = -rel;
  const int ret = (n < 0) ? 16 : 0;
  const int na = n < 0 ? -n : n;
  int bucket;
  if (na < 8) {
    bucket = ret + na;
  } else {
    int vl = 8 + (int)(log2((double)na * 0.125) * 2.0);
    vl = vl < 15 ? vl : 15;
    bucket = ret + vl;
  }
  table[idx] = rel_emb[bucket * 8 + h];
}

// ---------------------------------------------------------------------------
extern "C" void kernel_launch(void* const* d_in, const int* in_sizes, int n_in,
                              void* d_out, int out_size, void* d_ws, size_t ws_size,
                              hipStream_t stream)
{
  const float* x_in    = (const float*)d_in[0];
  const float* ln1_g   = (const float*)d_in[1];
  const float* ln1_b   = (const float*)d_in[2];
  const float* Wq      = (const float*)d_in[3];
  const float* Wkv     = (const float*)d_in[4];
  const float* Wo      = (const float*)d_in[5];
  const float* bo      = (const float*)d_in[6];
  const float* pre_proj= (const float*)d_in[7];
  const float* mem_k   = (const float*)d_in[8];
  const float* mem_v   = (const float*)d_in[9];
  const float* ln2_g   = (const float*)d_in[10];
  const float* ln2_b   = (const float*)d_in[11];
  const float* W1      = (const float*)d_in[12];
  const float* b1      = (const float*)d_in[13];
  const float* W2      = (const float*)d_in[14];
  const float* b2      = (const float*)d_in[15];
  const float* rel_emb = (const float*)d_in[16];

  char* p = (char*)d_ws;
  auto alloc = [&](size_t bytes) -> char* {
    char* r = p;
    p += (bytes + 255) & ~(size_t)255;
    return r;
  };

  // ~237 MB total with phase-disjoint aliasing
  float* x    = (float*)alloc((size_t)NROWS * NDIM * 4);          // 8.4 MB
  char*  RA   = alloc((size_t)NROWS * 2 * NDIM * 2);              // 8.4 MB: hs | obufs
  bf16*  hs    = (bf16*)RA;
  bf16*  obufs = (bf16*)RA;
  char*  RB   = alloc((size_t)NROWS * 2 * NFF * 2);               // 33.6 MB: (Qs+Ks) | tbufs
  bf16*  Qs    = (bf16*)RB;
  bf16*  Ks    = (bf16*)(RB + (size_t)NROWS * 2 * NDIM * 2);
  bf16*  tbufs = (bf16*)RB;
  float* kv   = (float*)alloc((size_t)NROWS * 2 * NDIM * 4);      // 16.8 MB
  float* S    = (float*)alloc((size_t)NSEQ * NHEADS * NJP * 4);   // 142.6 MB, [i][h][j]
  bf16*  WqkvT= (bf16*)alloc((size_t)2 * 3 * NDIM * 2 * NDIM * 2);// 6.3 MB (1536 x 1024 per layer)
  bf16*  WoT  = (bf16*)alloc((size_t)2 * NDIM * 2 * NDIM * 2);
  bf16*  W1T  = (bf16*)alloc((size_t)2 * NFF * 2 * NDIM * 2);
  bf16*  W2T  = (bf16*)alloc((size_t)2 * NDIM * 2 * NFF * 2);
  float* table= (float*)alloc((size_t)4111 * 8 * 4);

  // ---- prep ----
  hipMemcpyAsync(x, x_in, (size_t)NROWS * NDIM * 4, hipMemcpyDeviceToDevice, stream);
  build_bias<<<(4111 * 8 + 255) / 256, 256, 0, stream>>>(rel_emb, table);
  for (int l = 0; l < 2; l++) {
    bf16* WqkvT_l = WqkvT + (size_t)l * 3 * NDIM * 2 * NDIM;
    transpose_split<<<(NDIM * NDIM + 255) / 256, 256, 0, stream>>>(
        Wq + (size_t)l * NDIM * NDIM, WqkvT_l, NDIM, NDIM);                       // rows 0..511
    transpose_split<<<(2 * NDIM * NDIM + 255) / 256, 256, 0, stream>>>(
        Wkv + (size_t)l * NDIM * 2 * NDIM, WqkvT_l + (size_t)NDIM * 2 * NDIM,
        NDIM, 2 * NDIM);                                                           // rows 512..1535
    transpose_split<<<(NDIM * NDIM + 255) / 256, 256, 0, stream>>>(
        Wo + (size_t)l * NDIM * NDIM, WoT + (size_t)l * NDIM * 2 * NDIM, NDIM, NDIM);
    transpose_split<<<(NDIM * NFF + 255) / 256, 256, 0, stream>>>(
        W1 + (size_t)l * NDIM * NFF, W1T + (size_t)l * NFF * 2 * NDIM, NDIM, NFF);
    transpose_split<<<(NFF * NDIM + 255) / 256, 256, 0, stream>>>(
        W2 + (size_t)l * NFF * NDIM, W2T + (size_t)l * NDIM * 2 * NFF, NFF, NDIM);
  }

  // ---- layers ----
  for (int l = 0; l < 2; l++) {
    const bf16* WqkvT_l = WqkvT + (size_t)l * 3 * NDIM * 2 * NDIM;
    const bf16* WoT_l  = WoT + (size_t)l * NDIM * 2 * NDIM;
    const bf16* W1T_l  = W1T + (size_t)l * NFF * 2 * NDIM;
    const bf16* W2T_l  = W2T + (size_t)l * NDIM * 2 * NFF;
    const float* mem_v_l = mem_v + (size_t)l * NHEADS * NMEM * DHEAD;

    ln_kernel<<<NROWS / 4, 256, 0, stream>>>(x, ln1_g + l * NDIM, ln1_b + l * NDIM, hs);
    // merged QKV projection: N=1536 (cols 0-511 -> Qs split*0.125, 512-1535 -> kv fp32)
    gemm_split<128, 128, 2, 2, EPI_QKV><<<dim3(NROWS / 128, 12), 256, 0, stream>>>(
        hs, WqkvT_l, Qs, nullptr, kv, NDIM, 2 * NDIM, 2 * NDIM, 0, NDIM, NDIM);
    build_ks<<<(int)(((long long)NB * NJP * NDIM) / 256), 256, 0, stream>>>(
        kv, mem_k + (size_t)l * NHEADS * NMEM * DHEAD, Ks);

    for (int b = 0; b < NB; b++) {
      s_gemm_direct<<<dim3(NSEQ / 128, NJP / 128, NHEADS), 256, 0, stream>>>(
          Qs + (long long)b * NSEQ * 1024, Ks + (long long)b * NJP * 1024, S);
      mix_topk_gather<<<NSEQ, 512, 0, stream>>>(
          S, kv, mem_v_l, pre_proj + l * 64, table, obufs, b);
    }

    // x += obuf @ Wo + bo  (128x64 tiles -> 256 blocks)
    gemm_split<128, 64, 2, 2, EPI_RESID><<<dim3(NROWS / 128, NDIM / 64), 256, 0, stream>>>(
        obufs, WoT_l, x, bo + l * NDIM, nullptr, NDIM, 2 * NDIM, 2 * NDIM, NDIM, NDIM, NDIM);

    ln_kernel<<<NROWS / 4, 256, 0, stream>>>(x, ln2_g + l * NDIM, ln2_b + l * NDIM, hs);
    gemm_split<128, 128, 2, 2, EPI_GELUSPLIT><<<dim3(NROWS / 128, NFF / 128), 256, 0, stream>>>(
        hs, W1T_l, tbufs, b1 + l * NFF, nullptr, NDIM, 2 * NDIM, 2 * NDIM, NFF, NDIM, NDIM);
    // x += gelu @ W2 + b2  (128x64 tiles -> 256 blocks)
    gemm_split<128, 64, 2, 2, EPI_RESID><<<dim3(NROWS / 128, NDIM / 64), 256, 0, stream>>>(
        tbufs, W2T_l, x, b2 + l * NDIM, nullptr, NFF, 2 * NFF, 2 * NFF, NDIM, NFF, NFF);
  }

  hipMemcpyAsync(d_out, x, (size_t)out_size * 4, hipMemcpyDeviceToDevice, stream);
}

// Round 10
// 881.715 us; speedup vs baseline: 1.2819x; 1.0741x over previous
//
#include <hip/hip_runtime.h>
#include <cmath>

typedef __bf16 bf16;
typedef __attribute__((ext_vector_type(8))) __bf16 bf16x8;
typedef __attribute__((ext_vector_type(4))) __bf16 bf16x4;
typedef __attribute__((ext_vector_type(4))) float f32x4;

#define NB 2
#define NSEQ 2048
#define NDIM 512
#define NHEADS 8
#define DHEAD 64
#define NMEM 16
#define NJ 2064
#define NJP 2176        // 17*128
#define NFF 2048
#define NROWS (NB*NSEQ) // 4096
#define TBL 4111        // rel table width (rel+2047 in [0,4110])

enum { EPI_QKV = 0, EPI_GELUSPLIT = 1, EPI_RESID = 2 };

// ---------------------------------------------------------------------------
// Split-precision GEMM with double-buffered global_load_lds prefetch.
// EPI_QKV epilogue splits N=1536 into Qs(split,0.125) | Ks(split,direct) | kvV(fp32)
// ---------------------------------------------------------------------------
template<int BM, int BN, int WAVES_M, int WAVES_N, int EPI>
__global__ __launch_bounds__(256)
void gemm_split(const bf16* __restrict__ A, const bf16* __restrict__ B,
                void* __restrict__ Cv, const float* __restrict__ bias,
                void* __restrict__ Cv2, void* __restrict__ Cv3,
                int K, int lda, int ldb, int ldc, int loA, int loB)
{
  constexpr int BK = 32;
  constexpr int WM = BM / WAVES_M;
  constexpr int WN = BN / WAVES_N;
  constexpr int MF = WM / 16;
  constexpr int NF = WN / 16;
  constexpr int AI = (BM * BK * 2) / 4096;
  constexpr int BI = (BN * BK * 2) / 4096;
  __shared__ bf16 Ash[2][BM * BK];
  __shared__ bf16 Asl[2][BM * BK];
  __shared__ bf16 Bsh[2][BN * BK];
  __shared__ bf16 Bsl[2][BN * BK];

  const int bm0 = blockIdx.x * BM;
  const int bn0 = blockIdx.y * BN;
  const int t = threadIdx.x;
  const int wave = t >> 6, lane = t & 63;
  const int wr = wave / WAVES_N, wc = wave % WAVES_N;
  const int sr = t >> 2, sc = t & 3;
  const int frow = lane & 15, fk = (lane >> 4) * 8;

  auto stage = [&](int buf, int k0) {
#pragma unroll
    for (int qi = 0; qi < AI; ++qi) {
      const long long ro = (long long)(bm0 + qi * 64 + sr) * lda + (k0 + sc * 8);
      __builtin_amdgcn_global_load_lds(
          (const __attribute__((address_space(1))) void*)(A + ro),
          (__attribute__((address_space(3))) void*)(&Ash[buf][qi * 2048 + wave * 512]), 16, 0, 0);
      __builtin_amdgcn_global_load_lds(
          (const __attribute__((address_space(1))) void*)(A + ro + loA),
          (__attribute__((address_space(3))) void*)(&Asl[buf][qi * 2048 + wave * 512]), 16, 0, 0);
    }
#pragma unroll
    for (int qi = 0; qi < BI; ++qi) {
      const long long ro = (long long)(bn0 + qi * 64 + sr) * ldb + (k0 + sc * 8);
      __builtin_amdgcn_global_load_lds(
          (const __attribute__((address_space(1))) void*)(B + ro),
          (__attribute__((address_space(3))) void*)(&Bsh[buf][qi * 2048 + wave * 512]), 16, 0, 0);
      __builtin_amdgcn_global_load_lds(
          (const __attribute__((address_space(1))) void*)(B + ro + loB),
          (__attribute__((address_space(3))) void*)(&Bsl[buf][qi * 2048 + wave * 512]), 16, 0, 0);
    }
  };

  f32x4 acc[MF][NF] = {};

  stage(0, 0);
  __syncthreads();
  int cur = 0;
  for (int k0 = 0; k0 < K; k0 += BK) {
    if (k0 + BK < K) stage(cur ^ 1, k0 + BK);
    bf16x8 afh[MF], afl[MF], bfh[NF], bfl[NF];
#pragma unroll
    for (int m = 0; m < MF; m++) {
      afh[m] = *(const bf16x8*)(&Ash[cur][(wr * WM + m * 16 + frow) * BK + fk]);
      afl[m] = *(const bf16x8*)(&Asl[cur][(wr * WM + m * 16 + frow) * BK + fk]);
    }
#pragma unroll
    for (int n = 0; n < NF; n++) {
      bfh[n] = *(const bf16x8*)(&Bsh[cur][(wc * WN + n * 16 + frow) * BK + fk]);
      bfl[n] = *(const bf16x8*)(&Bsl[cur][(wc * WN + n * 16 + frow) * BK + fk]);
    }
#pragma unroll
    for (int m = 0; m < MF; m++)
#pragma unroll
      for (int n = 0; n < NF; n++) {
        acc[m][n] = __builtin_amdgcn_mfma_f32_16x16x32_bf16(afh[m], bfh[n], acc[m][n], 0, 0, 0);
        acc[m][n] = __builtin_amdgcn_mfma_f32_16x16x32_bf16(afl[m], bfh[n], acc[m][n], 0, 0, 0);
        acc[m][n] = __builtin_amdgcn_mfma_f32_16x16x32_bf16(afh[m], bfl[n], acc[m][n], 0, 0, 0);
      }
    __syncthreads();
    cur ^= 1;
  }

  // C/D layout: col=lane&15, row=(lane>>4)*4+reg
#pragma unroll
  for (int m = 0; m < MF; m++) {
#pragma unroll
    for (int n = 0; n < NF; n++) {
      const int row0 = bm0 + wr * WM + m * 16 + (lane >> 4) * 4;
      const int col = bn0 + wc * WN + n * 16 + (lane & 15);
#pragma unroll
      for (int r = 0; r < 4; r++) {
        const float v = acc[m][n][r];
        const long long i = row0 + r;
        if (EPI == EPI_QKV) {
          const int bb = (int)(i >> 11);
          const int il = (int)(i & 2047);
          if (col < NDIM) {              // Q -> Qs split (scale 0.125 folded)
            const float vq = v * 0.125f;
            bf16* base = (bf16*)Cv;
            const long long ih = i * (long long)(2 * NDIM) + col;
            bf16 h = (bf16)vq;
            base[ih] = h;
            base[ih + NDIM] = (bf16)(vq - (float)h);
          } else if (col < 2 * NDIM) {   // K -> Ks split, row j = il+16
            bf16* ks = (bf16*)Cv3;
            const long long ih = ((long long)bb * NJP + il + NMEM) * (long long)(2 * NDIM)
                               + (col - NDIM);
            bf16 h = (bf16)v;
            ks[ih] = h;
            ks[ih + NDIM] = (bf16)(v - (float)h);
          } else {                       // V -> kvV fp32
            ((float*)Cv2)[i * (long long)NDIM + (col - 2 * NDIM)] = v;
          }
        } else if (EPI == EPI_GELUSPLIT) {
          float u = v + bias[col];
          float gl = 0.5f * u * (1.0f + erff(u * 0.7071067811865476f));
          const long long ih = i * (long long)(2 * ldc) + col;
          bf16 h = (bf16)gl;
          ((bf16*)Cv)[ih] = h;
          ((bf16*)Cv)[ih + ldc] = (bf16)(gl - (float)h);
        } else {  // EPI_RESID
          float* xp = ((float*)Cv) + i * ldc + col;
          *xp = *xp + v + bias[col];
        }
      }
    }
  }
}

// ---------------------------------------------------------------------------
// Barrier-free direct-register S-GEMM: S_h(i,j) = q_h(i).k_h(j), K=64.
// grid (NSEQ/128, 17, 8); writes S[i][h][j].
// ---------------------------------------------------------------------------
__global__ __launch_bounds__(256)
void s_gemm_direct(const bf16* __restrict__ Qs, const bf16* __restrict__ Ks,
                   float* __restrict__ S)
{
  const int h = blockIdx.z;
  const int bm0 = blockIdx.x * 128;
  const int bn0 = blockIdx.y * 128;
  const int t = threadIdx.x;
  const int wave = t >> 6, lane = t & 63;
  const int wr = wave >> 1, wc = wave & 1;
  const int frow = lane & 15, fk = (lane >> 4) * 8;

  bf16x8 ah[4][2], al[4][2];
#pragma unroll
  for (int m = 0; m < 4; m++)
#pragma unroll
    for (int kk = 0; kk < 2; kk++) {
      const bf16* ap = Qs + (long long)(bm0 + wr * 64 + m * 16 + frow) * 1024
                     + h * 64 + kk * 32 + fk;
      ah[m][kk] = *(const bf16x8*)(ap);
      al[m][kk] = *(const bf16x8*)(ap + 512);
    }

  f32x4 acc[4][4] = {};
#pragma unroll
  for (int n = 0; n < 4; n++) {
    bf16x8 bh[2], bl[2];
#pragma unroll
    for (int kk = 0; kk < 2; kk++) {
      const bf16* bp = Ks + (long long)(bn0 + wc * 64 + n * 16 + frow) * 1024
                     + h * 64 + kk * 32 + fk;
      bh[kk] = *(const bf16x8*)(bp);
      bl[kk] = *(const bf16x8*)(bp + 512);
    }
#pragma unroll
    for (int m = 0; m < 4; m++)
#pragma unroll
      for (int kk = 0; kk < 2; kk++) {
        acc[m][n] = __builtin_amdgcn_mfma_f32_16x16x32_bf16(ah[m][kk], bh[kk], acc[m][n], 0, 0, 0);
        acc[m][n] = __builtin_amdgcn_mfma_f32_16x16x32_bf16(al[m][kk], bh[kk], acc[m][n], 0, 0, 0);
        acc[m][n] = __builtin_amdgcn_mfma_f32_16x16x32_bf16(ah[m][kk], bl[kk], acc[m][n], 0, 0, 0);
      }
  }

#pragma unroll
  for (int m = 0; m < 4; m++) {
#pragma unroll
    for (int n = 0; n < 4; n++) {
      const int row0 = bm0 + wr * 64 + m * 16 + (lane >> 4) * 4;
      const int col = bn0 + wc * 64 + n * 16 + (lane & 15);
#pragma unroll
      for (int r = 0; r < 4; r++)
        S[(long long)(row0 + r) * (NHEADS * NJP) + h * NJP + col] = acc[m][n][r];
    }
  }
}

// ---------------------------------------------------------------------------
// LayerNorm -> split bf16 (hi | lo), row stride 1024
// ---------------------------------------------------------------------------
__global__ __launch_bounds__(256)
void ln_kernel(const float* __restrict__ x, const float* __restrict__ g,
               const float* __restrict__ b, bf16* __restrict__ out)
{
  const int row = blockIdx.x * 4 + (threadIdx.x >> 6);
  const int lane = threadIdx.x & 63;
  const float* xr = x + (long long)row * NDIM;
  float4 a0 = ((const float4*)xr)[lane];
  float4 a1 = ((const float4*)xr)[lane + 64];
  float s = a0.x + a0.y + a0.z + a0.w + a1.x + a1.y + a1.z + a1.w;
  float ss = a0.x * a0.x + a0.y * a0.y + a0.z * a0.z + a0.w * a0.w
           + a1.x * a1.x + a1.y * a1.y + a1.z * a1.z + a1.w * a1.w;
#pragma unroll
  for (int d = 1; d < 64; d <<= 1) {
    s += __shfl_xor(s, d, 64);
    ss += __shfl_xor(ss, d, 64);
  }
  const float mean = s * (1.0f / NDIM);
  const float var = ss * (1.0f / NDIM) - mean * mean;
  const float rs = rsqrtf(var + 1e-5f);
  float4 g0 = ((const float4*)g)[lane], g1 = ((const float4*)g)[lane + 64];
  float4 b0 = ((const float4*)b)[lane], b1 = ((const float4*)b)[lane + 64];
  bf16* orow = out + (long long)row * (2 * NDIM);
  float y[8] = {
    (a0.x - mean) * rs * g0.x + b0.x, (a0.y - mean) * rs * g0.y + b0.y,
    (a0.z - mean) * rs * g0.z + b0.z, (a0.w - mean) * rs * g0.w + b0.w,
    (a1.x - mean) * rs * g1.x + b1.x, (a1.y - mean) * rs * g1.y + b1.y,
    (a1.z - mean) * rs * g1.z + b1.z, (a1.w - mean) * rs * g1.w + b1.w };
  bf16x4 h0, h1, l0, l1;
#pragma unroll
  for (int j = 0; j < 4; j++) {
    bf16 h = (bf16)y[j];      h0[j] = h;  l0[j] = (bf16)(y[j] - (float)h);
    bf16 h2 = (bf16)y[4 + j]; h1[j] = h2; l1[j] = (bf16)(y[4 + j] - (float)h2);
  }
  *(bf16x4*)(orow + lane * 4) = h0;
  *(bf16x4*)(orow + 256 + lane * 4) = h1;
  *(bf16x4*)(orow + 512 + lane * 4) = l0;
  *(bf16x4*)(orow + 768 + lane * 4) = l1;
}

// ---------------------------------------------------------------------------
// Ks edge rows: j<16 from mem_k (split), j in [2064,2176) zero. Both batches.
// ---------------------------------------------------------------------------
__global__ __launch_bounds__(256)
void ks_edges(const float* __restrict__ mem_k_l, bf16* __restrict__ Ks)
{
  const int idx = blockIdx.x * 256 + threadIdx.x;  // 2 * 128 * 512
  const int c = idx & 511;
  const int jj = (idx >> 9) & 127;
  const int bb = idx >> 16;
  const int j = (jj < NMEM) ? jj : (jj - NMEM + NJ);
  float kval = 0.f;
  if (jj < NMEM) kval = mem_k_l[((c >> 6) * NMEM + jj) * DHEAD + (c & 63)];
  bf16 hv = (bf16)kval;
  const long long ro = ((long long)bb * NJP + j) * (2 * NDIM) + c;
  Ks[ro] = hv;
  Ks[ro + NDIM] = (bf16)(kval - (float)hv);
}

// ---------------------------------------------------------------------------
// Fused talking-heads mix + bias + top-8 + softmax + sparse PV gather.
// Barrier-free: direct global reads of S[i][h][j] (contiguous 69.6 KB span,
// coalesced float4 per (h,t); 8 waves share lines via L1/L2). Bias from
// transposed table2[k][rel] (lane-consecutive). Branchless insertion,
// values-only butterfly, ballot recovery, fp32 V gather, split-bf16 out.
// ---------------------------------------------------------------------------
__global__ __launch_bounds__(512)
void mix_topk_gather(const float* __restrict__ S, const float* __restrict__ kvV,
                     const float* __restrict__ mem_v_l, const float* __restrict__ pp,
                     const float* __restrict__ table2, bf16* __restrict__ obufs,
                     int b)
{
  const int i = blockIdx.x;
  const int k = threadIdx.x >> 6;
  const int lane = threadIdx.x & 63;
  const float* srow = S + (long long)i * (NHEADS * NJP);

  float pk[8];
#pragma unroll
  for (int h = 0; h < 8; h++) pk[h] = pp[h * 8 + k];
  const float* t2k = table2 + k * TBL + (2047 - i);

  float v[34];
  // bias init (coalesced-ish: lane-consecutive scalar loads)
#pragma unroll
  for (int t = 0; t < 8; t++) {
    const int j0 = 256 * t + 4 * lane;
    v[4 * t + 0] = t2k[j0];
    v[4 * t + 1] = t2k[j0 + 1];
    v[4 * t + 2] = t2k[j0 + 2];
    v[4 * t + 3] = t2k[j0 + 3];
  }
  {
    const int j0 = 2048 + 2 * lane;
    const int jc = j0 < 2062 ? j0 : 2062;
    v[32] = t2k[jc];
    v[33] = t2k[jc + 1];
  }

  // mix: h outer, fully unrolled; loads independent within each h
#pragma unroll
  for (int h = 0; h < 8; h++) {
    const float* sp = srow + h * NJP;
    const float w = pk[h];
#pragma unroll
    for (int t = 0; t < 8; t++) {
      const float4 s4 = *(const float4*)(sp + 256 * t + 4 * lane);
      v[4 * t + 0] = fmaf(s4.x, w, v[4 * t + 0]);
      v[4 * t + 1] = fmaf(s4.y, w, v[4 * t + 1]);
      v[4 * t + 2] = fmaf(s4.z, w, v[4 * t + 2]);
      v[4 * t + 3] = fmaf(s4.w, w, v[4 * t + 3]);
    }
    const float2 s2 = *(const float2*)(sp + 2048 + 2 * lane);
    v[32] = fmaf(s2.x, w, v[32]);
    v[33] = fmaf(s2.y, w, v[33]);
  }
  {
    const int j0 = 2048 + 2 * lane;
    if (j0 >= NJ) v[32] = -1e30f;
    if (j0 + 1 >= NJ) v[33] = -1e30f;
  }

  // branchless descending insertion over all 34
  float t8[8];
#pragma unroll
  for (int m = 0; m < 8; m++) t8[m] = -3.0e38f;
#pragma unroll
  for (int e = 0; e < 34; e++) {
    float x = v[e];
#pragma unroll
    for (int m = 0; m < 8; m++) {
      const float hi = fmaxf(t8[m], x);
      x = fminf(t8[m], x);
      t8[m] = hi;
    }
  }

  // values-only butterfly: global top-8 (sorted desc) in every lane
#pragma unroll
  for (int d = 1; d < 64; d <<= 1) {
    float o[8], m8[8];
#pragma unroll
    for (int m = 0; m < 8; m++) o[m] = __shfl_xor(t8[m], d, 64);
#pragma unroll
    for (int m = 0; m < 8; m++) m8[m] = fmaxf(t8[m], o[7 - m]);
#define CX(a, bq) { float hi = fmaxf(m8[a], m8[bq]); float lo = fminf(m8[a], m8[bq]); m8[a] = hi; m8[bq] = lo; }
    CX(0, 4) CX(1, 5) CX(2, 6) CX(3, 7)
    CX(0, 2) CX(1, 3) CX(4, 6) CX(5, 7)
    CX(0, 1) CX(2, 3) CX(4, 5) CX(6, 7)
#undef CX
#pragma unroll
    for (int m = 0; m < 8; m++) t8[m] = m8[m];
  }
  const float mx = t8[0];
  const float thr = t8[7];
  float denom = 0.f;
#pragma unroll
  for (int m = 0; m < 8; m++) denom += __expf(t8[m] - mx);
  const float inv = 1.0f / denom;

  // index recovery + gather (~8 hits total)
  float acc = 0.f;
#pragma unroll
  for (int t = 0; t < 8; t++) {
#pragma unroll
    for (int e = 0; e < 4; e++) {
      unsigned long long mball = __ballot(v[t * 4 + e] >= thr);
      while (mball) {
        const int l = __builtin_ctzll(mball);
        mball &= mball - 1;
        const int jj = 256 * t + 4 * l + e;
        const float sv = __shfl(v[t * 4 + e], l);
        const float w = __expf(sv - mx) * inv;
        const float vv = (jj < NMEM)
            ? mem_v_l[(k * NMEM + jj) * DHEAD + lane]
            : kvV[(long long)(b * NSEQ + (jj - NMEM)) * NDIM + k * DHEAD + lane];
        acc = fmaf(w, vv, acc);
      }
    }
  }
#pragma unroll
  for (int e = 0; e < 2; e++) {
    unsigned long long mball = __ballot(v[32 + e] >= thr);
    while (mball) {
      const int l = __builtin_ctzll(mball);
      mball &= mball - 1;
      const int jj = 2048 + 2 * l + e;
      const float sv = __shfl(v[32 + e], l);
      const float w = __expf(sv - mx) * inv;
      const float vv = (jj < NMEM)
          ? mem_v_l[(k * NMEM + jj) * DHEAD + lane]
          : kvV[(long long)(b * NSEQ + (jj - NMEM)) * NDIM + k * DHEAD + lane];
      acc = fmaf(w, vv, acc);
    }
  }

  const long long orow = (long long)(b * NSEQ + i) * (2 * NDIM) + k * DHEAD + lane;
  bf16 h = (bf16)acc;
  obufs[orow] = h;
  obufs[orow + NDIM] = (bf16)(acc - (float)h);
}

// ---------------------------------------------------------------------------
// fp32 weight (R x C row-major) -> split-transposed bf16 (C x 2R)
// ---------------------------------------------------------------------------
__global__ __launch_bounds__(256)
void transpose_split(const float* __restrict__ in, bf16* __restrict__ out,
                     int R, int C)
{
  const long long idx = (long long)blockIdx.x * 256 + threadIdx.x;
  if (idx >= (long long)R * C) return;
  const int r = (int)(idx / C);
  const int c = (int)(idx % C);
  float v = in[idx];
  bf16 h = (bf16)v;
  out[(long long)c * (2 * R) + r] = h;
  out[(long long)c * (2 * R) + R + r] = (bf16)(v - (float)h);
}

// ---------------------------------------------------------------------------
// T5 bias table, TRANSPOSED: table2[k][rel+2047]; exact boundaries via log2
// ---------------------------------------------------------------------------
__global__ __launch_bounds__(256)
void build_bias2(const float* __restrict__ rel_emb, float* __restrict__ table2)
{
  const int idx = blockIdx.x * 256 + threadIdx.x;
  if (idx >= 8 * TBL) return;
  const int k = idx / TBL;
  const int rel = (idx % TBL) - 2047;
  const int n = -rel;
  const int ret = (n < 0) ? 16 : 0;
  const int na = n < 0 ? -n : n;
  int bucket;
  if (na < 8) {
    bucket = ret + na;
  } else {
    int vl = 8 + (int)(log2((double)na * 0.125) * 2.0);
    vl = vl < 15 ? vl : 15;
    bucket = ret + vl;
  }
  table2[idx] = rel_emb[bucket * 8 + k];
}

// ---------------------------------------------------------------------------
extern "C" void kernel_launch(void* const* d_in, const int* in_sizes, int n_in,
                              void* d_out, int out_size, void* d_ws, size_t ws_size,
                              hipStream_t stream)
{
  const float* x_in    = (const float*)d_in[0];
  const float* ln1_g   = (const float*)d_in[1];
  const float* ln1_b   = (const float*)d_in[2];
  const float* Wq      = (const float*)d_in[3];
  const float* Wkv     = (const float*)d_in[4];
  const float* Wo      = (const float*)d_in[5];
  const float* bo      = (const float*)d_in[6];
  const float* pre_proj= (const float*)d_in[7];
  const float* mem_k   = (const float*)d_in[8];
  const float* mem_v   = (const float*)d_in[9];
  const float* ln2_g   = (const float*)d_in[10];
  const float* ln2_b   = (const float*)d_in[11];
  const float* W1      = (const float*)d_in[12];
  const float* b1      = (const float*)d_in[13];
  const float* W2      = (const float*)d_in[14];
  const float* b2      = (const float*)d_in[15];
  const float* rel_emb = (const float*)d_in[16];

  char* p = (char*)d_ws;
  auto alloc = [&](size_t bytes) -> char* {
    char* r = p;
    p += (bytes + 255) & ~(size_t)255;
    return r;
  };

  float* x    = (float*)alloc((size_t)NROWS * NDIM * 4);          // 8.4 MB
  char*  RA   = alloc((size_t)NROWS * 2 * NDIM * 2);              // 8.4 MB: hs | obufs
  bf16*  hs    = (bf16*)RA;
  bf16*  obufs = (bf16*)RA;
  char*  RB   = alloc((size_t)NROWS * 2 * NFF * 2);               // 33.6 MB: (Qs+Ks) | tbufs
  bf16*  Qs    = (bf16*)RB;
  bf16*  Ks    = (bf16*)(RB + (size_t)NROWS * 2 * NDIM * 2);
  bf16*  tbufs = (bf16*)RB;
  float* kvV  = (float*)alloc((size_t)NROWS * NDIM * 4);          // 8.4 MB (V only)
  float* S    = (float*)alloc((size_t)NSEQ * NHEADS * NJP * 4);   // 142.6 MB, [i][h][j]
  bf16*  WqkvT= (bf16*)alloc((size_t)2 * 3 * NDIM * 2 * NDIM * 2);
  bf16*  WoT  = (bf16*)alloc((size_t)2 * NDIM * 2 * NDIM * 2);
  bf16*  W1T  = (bf16*)alloc((size_t)2 * NFF * 2 * NDIM * 2);
  bf16*  W2T  = (bf16*)alloc((size_t)2 * NDIM * 2 * NFF * 2);
  float* table2= (float*)alloc((size_t)8 * TBL * 4);

  // ---- prep ----
  hipMemcpyAsync(x, x_in, (size_t)NROWS * NDIM * 4, hipMemcpyDeviceToDevice, stream);
  build_bias2<<<(8 * TBL + 255) / 256, 256, 0, stream>>>(rel_emb, table2);
  for (int l = 0; l < 2; l++) {
    bf16* WqkvT_l = WqkvT + (size_t)l * 3 * NDIM * 2 * NDIM;
    transpose_split<<<(NDIM * NDIM + 255) / 256, 256, 0, stream>>>(
        Wq + (size_t)l * NDIM * NDIM, WqkvT_l, NDIM, NDIM);
    transpose_split<<<(2 * NDIM * NDIM + 255) / 256, 256, 0, stream>>>(
        Wkv + (size_t)l * NDIM * 2 * NDIM, WqkvT_l + (size_t)NDIM * 2 * NDIM,
        NDIM, 2 * NDIM);
    transpose_split<<<(NDIM * NDIM + 255) / 256, 256, 0, stream>>>(
        Wo + (size_t)l * NDIM * NDIM, WoT + (size_t)l * NDIM * 2 * NDIM, NDIM, NDIM);
    transpose_split<<<(NDIM * NFF + 255) / 256, 256, 0, stream>>>(
        W1 + (size_t)l * NDIM * NFF, W1T + (size_t)l * NFF * 2 * NDIM, NDIM, NFF);
    transpose_split<<<(NFF * NDIM + 255) / 256, 256, 0, stream>>>(
        W2 + (size_t)l * NFF * NDIM, W2T + (size_t)l * NDIM * 2 * NFF, NFF, NDIM);
  }

  // ---- layers ----
  for (int l = 0; l < 2; l++) {
    const bf16* WqkvT_l = WqkvT + (size_t)l * 3 * NDIM * 2 * NDIM;
    const bf16* WoT_l  = WoT + (size_t)l * NDIM * 2 * NDIM;
    const bf16* W1T_l  = W1T + (size_t)l * NFF * 2 * NDIM;
    const bf16* W2T_l  = W2T + (size_t)l * NDIM * 2 * NFF;
    const float* mem_v_l = mem_v + (size_t)l * NHEADS * NMEM * DHEAD;

    ln_kernel<<<NROWS / 4, 256, 0, stream>>>(x, ln1_g + l * NDIM, ln1_b + l * NDIM, hs);
    // merged QKV: cols 0-511 -> Qs split, 512-1023 -> Ks split, 1024-1535 -> kvV
    gemm_split<128, 128, 2, 2, EPI_QKV><<<dim3(NROWS / 128, 12), 256, 0, stream>>>(
        hs, WqkvT_l, Qs, nullptr, kvV, Ks, NDIM, 2 * NDIM, 2 * NDIM, 0, NDIM, NDIM);
    ks_edges<<<(2 * 128 * 512) / 256, 256, 0, stream>>>(
        mem_k + (size_t)l * NHEADS * NMEM * DHEAD, Ks);

    for (int b = 0; b < NB; b++) {
      s_gemm_direct<<<dim3(NSEQ / 128, NJP / 128, NHEADS), 256, 0, stream>>>(
          Qs + (long long)b * NSEQ * 1024, Ks + (long long)b * NJP * 1024, S);
      mix_topk_gather<<<NSEQ, 512, 0, stream>>>(
          S, kvV, mem_v_l, pre_proj + l * 64, table2, obufs, b);
    }

    gemm_split<128, 64, 2, 2, EPI_RESID><<<dim3(NROWS / 128, NDIM / 64), 256, 0, stream>>>(
        obufs, WoT_l, x, bo + l * NDIM, nullptr, nullptr,
        NDIM, 2 * NDIM, 2 * NDIM, NDIM, NDIM, NDIM);

    ln_kernel<<<NROWS / 4, 256, 0, stream>>>(x, ln2_g + l * NDIM, ln2_b + l * NDIM, hs);
    gemm_split<128, 128, 2, 2, EPI_GELUSPLIT><<<dim3(NROWS / 128, NFF / 128), 256, 0, stream>>>(
        hs, W1T_l, tbufs, b1 + l * NFF, nullptr, nullptr,
        NDIM, 2 * NDIM, 2 * NDIM, NFF, NDIM, NDIM);
    gemm_split<128, 64, 2, 2, EPI_RESID><<<dim3(NROWS / 128, NDIM / 64), 256, 0, stream>>>(
        tbufs, W2T_l, x, b2 + l * NDIM, nullptr, nullptr,
        NFF, 2 * NFF, 2 * NFF, NDIM, NFF, NFF);
  }

  hipMemcpyAsync(d_out, x, (size_t)out_size * 4, hipMemcpyDeviceToDevice, stream);
}